// Round 3
// baseline (5654.005 us; speedup 1.0000x reference)
//
#include <hip/hip_runtime.h>

typedef short bf16x8 __attribute__((ext_vector_type(8)));
typedef float f32x4 __attribute__((ext_vector_type(4)));
typedef unsigned u32x4 __attribute__((ext_vector_type(4)));

#define T_STEPS 1024
#define NBATCH  64
#define HID     1024
#define NIN     27
#define RINGN   32
#define RINGLO  4
#define LAG     8
#define BPG     16
#define JT      16

#define RINGHI_BYTES ((size_t)RINGN * NBATCH * HID * 2)        // 4 MiB
#define RINGLO_BYTES ((size_t)RINGLO * NBATCH * HID * 2)       // 512 KiB
#define FLAGS_BYTES  ((size_t)256 * 16 * sizeof(int))          // 16 KiB
#define WS_NEED      (RINGHI_BYTES + RINGLO_BYTES + FLAGS_BYTES)

__device__ __forceinline__ unsigned short f2bf(float f) {
    unsigned u = __float_as_uint(f);
    unsigned r = u + 0x7FFFu + ((u >> 16) & 1u);
    return (unsigned short)(r >> 16);
}
__device__ __forceinline__ float bf2f(unsigned short h) {
    return __uint_as_float(((unsigned)h) << 16);
}

// ---- system-coherent (cross-XCD) memory ops: sc0 sc1 bypass L1/L2 ----
__device__ __forceinline__ void ld_b128_sys(const void* p, u32x4& v) {
    asm volatile("global_load_dwordx4 %0, %1, off sc0 sc1" : "=v"(v) : "v"(p));
}
__device__ __forceinline__ void ld_b32_sys(const void* p, unsigned& v) {
    asm volatile("global_load_dword %0, %1, off sc0 sc1" : "=v"(v) : "v"(p));
}
__device__ __forceinline__ int ld_flag_sys(const int* p) {
    int v;
    asm volatile("global_load_dword %0, %1, off sc0 sc1\n\ts_waitcnt vmcnt(0)"
                 : "=v"(v) : "v"(p) : "memory");
    return v;
}
__device__ __forceinline__ void st_b32_sys(void* p, unsigned v) {
    asm volatile("global_store_dword %0, %1, off sc0 sc1" :: "v"(p), "v"(v) : "memory");
}
__device__ __forceinline__ void wait_vm0() {
    asm volatile("s_waitcnt vmcnt(0)" ::: "memory");
    __builtin_amdgcn_sched_barrier(0);   // keep consumers below the wait (rule #18)
}

// Persistent GRU: 256 WGs = 4 batch-groups x 64 j-slices. W_hh slice (48x1024
// bf16) register-resident per WG. h carried exactly in fp32 per-thread; ring
// holds hi/lo bf16 h (32-slot hi ring doubles as y_hat history for the fused
// delayed decode). ALL cross-WG traffic via sc0/sc1 system-coherent asm ops.
__global__ __launch_bounds__(256, 1)
void gru_persist(const float* __restrict__ x,
                 const int* __restrict__ delays,
                 const float* __restrict__ W_ih,
                 const float* __restrict__ W_hh,
                 const float* __restrict__ b_ih,
                 const float* __restrict__ b_hh,
                 const float* __restrict__ W_dec,
                 float* __restrict__ out,
                 unsigned short* __restrict__ ring_hi,
                 unsigned short* __restrict__ ring_lo,
                 int* __restrict__ flags)
{
    const int tid  = threadIdx.x;
    const int lane = tid & 63;
    const int kq   = tid >> 6;          // wave id = K-quarter (0..3)
    const int gb   = blockIdx.x >> 6;   // batch group (0..3)
    const int gn   = blockIdx.x & 63;   // j-slice (0..63)
    const int j0   = gn * JT;
    const int l15  = lane & 15;
    const int lhi  = lane >> 4;

    __shared__ f32x4 red[13 * 64];      // 12 = 3 gates x 4 waves, +1 = i_n (x-part)
    __shared__ float ylds[256];         // decode y quarter-row
    __shared__ float decp[256];         // decode partials [jg][o]
    __shared__ float bias_lds[64];
    __shared__ float hstage[16][16];    // [bl][jl] fp32 h_new for the packers

    // ---- persistent W_hh bf16 fragments: 3 gates x 8 K-chunks ----
    bf16x8 wHH[3][8];
    #pragma unroll
    for (int n = 0; n < 3; ++n) {
        const float* wrow = W_hh + (size_t)(n * HID + j0 + l15) * HID;
        #pragma unroll
        for (int c = 0; c < 8; ++c) {
            const float* wr = wrow + kq * 256 + c * 32 + lhi * 8;
            #pragma unroll
            for (int jj = 0; jj < 8; ++jj) wHH[n][c][jj] = (short)f2bf(wr[jj]);
        }
    }
    bf16x8 wXH[3];
    #pragma unroll
    for (int n = 0; n < 3; ++n) {
        const float* wrow = W_ih + (size_t)(n * HID + j0 + l15) * NIN;
        #pragma unroll
        for (int jj = 0; jj < 8; ++jj) {
            const int kk = lhi * 8 + jj;
            wXH[n][jj] = (kk < NIN) ? (short)f2bf(wrow[kk]) : (short)0;
        }
    }
    if (tid < 16) {
        bias_lds[tid]      = b_ih[j0 + tid] + b_hh[j0 + tid];               // r
        bias_lds[16 + tid] = b_ih[HID + j0 + tid] + b_hh[HID + j0 + tid];   // z
        bias_lds[32 + tid] = b_ih[2 * HID + j0 + tid];                      // n (x side)
        bias_lds[48 + tid] = b_hh[2 * HID + j0 + tid];                      // n (h side)
    }
    // ---- fused decode assignment ----
    const int bdec  = gb * BPG + (gn >> 2);
    const int qdec  = gn & 3;
    const int d_del = delays[bdec];     // harness delivers integers as int32
    const int odec  = tid & 31;
    const int jgd   = tid >> 5;
    float wd[32];
    #pragma unroll
    for (int jj = 0; jj < 32; ++jj)
        wd[jj] = (odec < NIN) ? W_dec[(size_t)odec * HID + qdec * 256 + jgd * 32 + jj] : 0.f;

    const int jl = l15;
    const int bl = kq * 4 + lhi;
    const int arow = gb * BPG + l15;    // A-fragment row = batch-in-group

    int* myflag = flags + (gb * 64 + gn) * 16;
    const int* pollflag = flags + (gb * 64 + lane) * 16;  // lane -> one producer WG

    float hprev = 0.f;
    bool dead = false;

    __syncthreads();

    #pragma clang loop unroll(disable)
    for (int t = 0; t < T_STEPS + LAG; ++t) {
        const int target = (t < T_STEPS) ? t : T_STEPS;
        // ---- wait: all 64 producer WGs of this batch group finished t-1 ----
        if (target > 0 && !dead) {
            int iter = 0;
            for (;;) {
                int v = ld_flag_sys(pollflag);
                if (__all(v >= target)) break;
                if (++iter > (1 << 18)) { dead = true; break; }
                __builtin_amdgcn_s_sleep(8);
            }
        }

        const int slot_prev  = (t + RINGN  - 1) & (RINGN  - 1);
        const int slot_prevL = (t + RINGLO - 1) & (RINGLO - 1);
        const int t_dec = t - LAG;

        // ---- issue all coherent loads, then one wait ----
        u32x4 rawH[8], rawL[8];
        if (t < T_STEPS) {
            const unsigned short* aH = ring_hi + ((size_t)(slot_prev  * NBATCH + arow)) * HID
                                     + kq * 256 + lhi * 8;
            const unsigned short* aL = ring_lo + ((size_t)(slot_prevL * NBATCH + arow)) * HID
                                     + kq * 256 + lhi * 8;
            #pragma unroll
            for (int c = 0; c < 8; ++c) ld_b128_sys(aH + c * 32, rawH[c]);
            #pragma unroll
            for (int c = 0; c < 8; ++c) ld_b128_sys(aL + c * 32, rawL[c]);
        }
        unsigned ydw = 0;
        if (t_dec >= 0 && tid < 128) {
            const int tau = (t_dec < d_del) ? t_dec : (t_dec - d_del);
            const unsigned* yrow = (const unsigned*)(ring_hi
                + ((size_t)((tau & (RINGN - 1)) * NBATCH + bdec)) * HID + qdec * 256);
            ld_b32_sys(yrow + tid, ydw);
        }
        wait_vm0();

        f32x4 acc0 = {0.f, 0.f, 0.f, 0.f};
        f32x4 acc1 = acc0, acc2 = acc0, acc2x = acc0;

        if (t < T_STEPS) {
            #pragma unroll
            for (int c = 0; c < 8; ++c) {       // W . h_hi
                bf16x8 a = __builtin_bit_cast(bf16x8, rawH[c]);
                acc0 = __builtin_amdgcn_mfma_f32_16x16x32_bf16(a, wHH[0][c], acc0, 0, 0, 0);
                acc1 = __builtin_amdgcn_mfma_f32_16x16x32_bf16(a, wHH[1][c], acc1, 0, 0, 0);
                acc2 = __builtin_amdgcn_mfma_f32_16x16x32_bf16(a, wHH[2][c], acc2, 0, 0, 0);
            }
            #pragma unroll
            for (int c = 0; c < 8; ++c) {       // W . h_lo
                bf16x8 a = __builtin_bit_cast(bf16x8, rawL[c]);
                acc0 = __builtin_amdgcn_mfma_f32_16x16x32_bf16(a, wHH[0][c], acc0, 0, 0, 0);
                acc1 = __builtin_amdgcn_mfma_f32_16x16x32_bf16(a, wHH[1][c], acc1, 0, 0, 0);
                acc2 = __builtin_amdgcn_mfma_f32_16x16x32_bf16(a, wHH[2][c], acc2, 0, 0, 0);
            }
            if (kq == 0) {                      // fused x-path (wave 0 only)
                const float* xr = x + ((size_t)arow * T_STEPS + t) * NIN;
                bf16x8 axH, axL;
                #pragma unroll
                for (int jj = 0; jj < 8; ++jj) {
                    const int kk = lhi * 8 + jj;
                    if (kk < NIN) {
                        float f = xr[kk];
                        unsigned short hi = f2bf(f);
                        axH[jj] = (short)hi;
                        axL[jj] = (short)f2bf(f - bf2f(hi));
                    } else { axH[jj] = 0; axL[jj] = 0; }
                }
                acc0  = __builtin_amdgcn_mfma_f32_16x16x32_bf16(axH, wXH[0], acc0, 0, 0, 0);
                acc1  = __builtin_amdgcn_mfma_f32_16x16x32_bf16(axH, wXH[1], acc1, 0, 0, 0);
                acc2x = __builtin_amdgcn_mfma_f32_16x16x32_bf16(axH, wXH[2], acc2x, 0, 0, 0);
                acc0  = __builtin_amdgcn_mfma_f32_16x16x32_bf16(axL, wXH[0], acc0, 0, 0, 0);
                acc1  = __builtin_amdgcn_mfma_f32_16x16x32_bf16(axL, wXH[1], acc1, 0, 0, 0);
                acc2x = __builtin_amdgcn_mfma_f32_16x16x32_bf16(axL, wXH[2], acc2x, 0, 0, 0);
            }
            red[(0 * 4 + kq) * 64 + lane] = acc0;
            red[(1 * 4 + kq) * 64 + lane] = acc1;
            red[(2 * 4 + kq) * 64 + lane] = acc2;
            if (kq == 0) red[12 * 64 + lane] = acc2x;
        }
        if (t_dec >= 0 && tid < 128) {
            ylds[2 * tid]     = bf2f((unsigned short)(ydw & 0xFFFFu));
            ylds[2 * tid + 1] = bf2f((unsigned short)(ydw >> 16));
        }
        __syncthreads();   // sync1

        if (t < T_STEPS) {
            // reduce 4 K-quarter partials; C layout: col=lane&15, row=(lane>>4)*4+reg
            const float* redf = (const float*)red;
            const int ridx = (jl + 16 * (bl >> 2)) * 4 + (bl & 3);
            float gr = 0.f, gz = 0.f, gh_n = 0.f;
            #pragma unroll
            for (int w = 0; w < 4; ++w) {
                gr   += redf[((0 * 4 + w) * 64) * 4 + ridx];
                gz   += redf[((1 * 4 + w) * 64) * 4 + ridx];
                gh_n += redf[((2 * 4 + w) * 64) * 4 + ridx];
            }
            const float i_n = redf[(12 * 64) * 4 + ridx];
            const float r  = 1.f / (1.f + __expf(-(gr + bias_lds[jl])));
            const float z  = 1.f / (1.f + __expf(-(gz + bias_lds[16 + jl])));
            const float nn = tanhf(i_n + bias_lds[32 + jl] + r * (gh_n + bias_lds[48 + jl]));
            const float hnew = (1.f - z) * nn + z * hprev;
            hprev = hnew;
            hstage[bl][jl] = hnew;
        }
        if (t_dec >= 0 && odec < NIN) {
            float p = 0.f;
            #pragma unroll
            for (int k = 0; k < 32; ++k) p += ylds[jgd * 32 + k] * wd[k];
            decp[jgd * 32 + odec] = p;
        }
        __syncthreads();   // sync2

        if (t < T_STEPS && tid < 128) {
            const int blp = tid >> 3, jp = tid & 7;
            const float h0 = hstage[blp][2 * jp], h1 = hstage[blp][2 * jp + 1];
            const unsigned short h0h = f2bf(h0), h1h = f2bf(h1);
            const unsigned dhi = (unsigned)h0h | ((unsigned)h1h << 16);
            const unsigned dlo = (unsigned)f2bf(h0 - bf2f(h0h))
                               | ((unsigned)f2bf(h1 - bf2f(h1h)) << 16);
            const int bg = gb * BPG + blp;
            unsigned* rh = (unsigned*)ring_hi;
            unsigned* rl = (unsigned*)ring_lo;
            const size_t ih = ((size_t)((t & (RINGN - 1)) * NBATCH + bg)) * (HID / 2)
                            + (j0 >> 1) + jp;
            const size_t il = ((size_t)((t & (RINGLO - 1)) * NBATCH + bg)) * (HID / 2)
                            + (j0 >> 1) + jp;
            st_b32_sys(rh + ih, dhi);
            st_b32_sys(rl + il, dlo);
        }
        wait_vm0();        // drain asm stores (compiler doesn't track them)
        __syncthreads();   // sync3: all ring data at the coherent point

        if (t < T_STEPS && tid == 0)
            st_b32_sys(myflag, (unsigned)(t + 1));

        if (t_dec >= 0 && tid < NIN) {
            float v = 0.f;
            #pragma unroll
            for (int jg = 0; jg < 8; ++jg) v += decp[jg * 32 + tid];
            atomicAdd(out + ((size_t)bdec * T_STEPS + t_dec) * NIN + tid, v);
        }
    }
}

__global__ void fill_out_kernel(float* __restrict__ out, const float* __restrict__ b_dec, int n)
{
    int idx = blockIdx.x * blockDim.x + threadIdx.x;
    if (idx < n) out[idx] = b_dec[idx % NIN];
}

extern "C" void kernel_launch(void* const* d_in, const int* in_sizes, int n_in,
                              void* d_out, int out_size, void* d_ws, size_t ws_size,
                              hipStream_t stream)
{
    (void)in_sizes; (void)n_in;
    const float* xx    = (const float*)d_in[0];
    const int*   dl    = (const int*)d_in[1];     // harness: integer -> int32
    const float* W_ih  = (const float*)d_in[2];
    const float* W_hh  = (const float*)d_in[3];
    const float* b_ih  = (const float*)d_in[4];
    const float* b_hh  = (const float*)d_in[5];
    const float* W_dec = (const float*)d_in[6];
    const float* b_dec = (const float*)d_in[7];
    float* out = (float*)d_out;

    if (ws_size < WS_NEED) return;   // diagnostic: absmax stays 0.206 if too small

    unsigned short* ring_hi = (unsigned short*)d_ws;
    unsigned short* ring_lo = (unsigned short*)((char*)d_ws + RINGHI_BYTES);
    int*            flags   = (int*)((char*)d_ws + RINGHI_BYTES + RINGLO_BYTES);

    const size_t slot_bytes = (size_t)NBATCH * HID * 2;   // 128 KiB
    // zero h(-1) slots (hi ring slot 31, lo ring slot 3) and flags
    hipMemsetAsync((char*)d_ws + (size_t)(RINGN - 1) * slot_bytes, 0, slot_bytes, stream);
    hipMemsetAsync((char*)d_ws + RINGHI_BYTES + (size_t)(RINGLO - 1) * slot_bytes, 0,
                   slot_bytes + FLAGS_BYTES, stream);

    fill_out_kernel<<<dim3((out_size + 255) / 256), dim3(256), 0, stream>>>(out, b_dec, out_size);

    void* args[] = {(void*)&xx, (void*)&dl, (void*)&W_ih, (void*)&W_hh, (void*)&b_ih,
                    (void*)&b_hh, (void*)&W_dec, (void*)&out, (void*)&ring_hi,
                    (void*)&ring_lo, (void*)&flags};
    hipError_t e = hipLaunchCooperativeKernel((void*)gru_persist, dim3(256), dim3(256),
                                              args, 0, stream);
    if (e != hipSuccess) {
        gru_persist<<<dim3(256), dim3(256), 0, stream>>>(xx, dl, W_ih, W_hh, b_ih, b_hh,
                                                         W_dec, out, ring_hi, ring_lo, flags);
    }
}

// Round 4
// 4961.851 us; speedup vs baseline: 1.1395x; 1.1395x over previous
//
#include <hip/hip_runtime.h>

typedef short bf16x8 __attribute__((ext_vector_type(8)));
typedef float f32x4 __attribute__((ext_vector_type(4)));
typedef unsigned u32x4 __attribute__((ext_vector_type(4)));

#define T_STEPS 1024
#define NBATCH  64
#define HID     1024
#define NIN     27
#define RINGN   32
#define RINGLO  4
#define LAG     8
#define BPG     16
#define JT      16

#define RINGHI_BYTES ((size_t)RINGN * NBATCH * HID * 2)        // 4 MiB
#define RINGLO_BYTES ((size_t)RINGLO * NBATCH * HID * 2)       // 512 KiB
#define FLAGS_BYTES  ((size_t)256 * 16 * sizeof(int))          // 16 KiB
#define WS_NEED      (RINGHI_BYTES + RINGLO_BYTES + FLAGS_BYTES)

__device__ __forceinline__ unsigned short f2bf(float f) {
    unsigned u = __float_as_uint(f);
    unsigned r = u + 0x7FFFu + ((u >> 16) & 1u);
    return (unsigned short)(r >> 16);
}
__device__ __forceinline__ float bf2f(unsigned short h) {
    return __uint_as_float(((unsigned)h) << 16);
}

// ---- system-coherent (cross-XCD) memory ops: sc0 sc1 bypass L1/L2 ----
__device__ __forceinline__ void ld_b128_sys(const void* p, u32x4& v) {
    asm volatile("global_load_dwordx4 %0, %1, off sc0 sc1" : "=v"(v) : "v"(p));
}
__device__ __forceinline__ void ld_b32_sys(const void* p, unsigned& v) {
    asm volatile("global_load_dword %0, %1, off sc0 sc1" : "=v"(v) : "v"(p));
}
__device__ __forceinline__ int ld_flag_sys(const int* p) {
    int v;
    asm volatile("global_load_dword %0, %1, off sc0 sc1\n\ts_waitcnt vmcnt(0)"
                 : "=v"(v) : "v"(p) : "memory");
    return v;
}
__device__ __forceinline__ void st_b32_sys(void* p, unsigned v) {
    asm volatile("global_store_dword %0, %1, off sc0 sc1" :: "v"(p), "v"(v) : "memory");
}
__device__ __forceinline__ void st_b16_sys(void* p, unsigned v) {
    asm volatile("global_store_short %0, %1, off sc0 sc1" :: "v"(p), "v"(v) : "memory");
}
__device__ __forceinline__ void wait_vm0() {
    asm volatile("s_waitcnt vmcnt(0)" ::: "memory");
    __builtin_amdgcn_sched_barrier(0);   // rule #18: pin consumers below the wait
}
__device__ __forceinline__ void wait_vm8() {
    asm volatile("s_waitcnt vmcnt(8)" ::: "memory");
    __builtin_amdgcn_sched_barrier(0);
}

// Persistent GRU: 256 WGs = 4 batch-groups x 64 j-slices. W_hh slice (48x1024
// bf16) register-resident per WG. h carried exactly in fp32 per-thread; ring
// holds hi/lo bf16 h (32-slot hi ring doubles as y_hat history for the fused
// delayed decode). ALL cross-WG traffic via sc0/sc1 system-coherent asm ops.
// Critical chain per step: spin-poll -> ring loads -> MFMA -> reduce/gates ->
// direct h stores -> drain -> flag. Decode + x-path run in the shadow.
__global__ __launch_bounds__(256, 1)
void gru_persist(const float* __restrict__ x,
                 const int* __restrict__ delays,
                 const float* __restrict__ W_ih,
                 const float* __restrict__ W_hh,
                 const float* __restrict__ b_ih,
                 const float* __restrict__ b_hh,
                 const float* __restrict__ W_dec,
                 float* __restrict__ out,
                 unsigned short* __restrict__ ring_hi,
                 unsigned short* __restrict__ ring_lo,
                 int* __restrict__ flags)
{
    const int tid  = threadIdx.x;
    const int lane = tid & 63;
    const int kq   = tid >> 6;          // wave id = K-quarter (0..3)
    const int gb   = blockIdx.x >> 6;   // batch group (0..3)
    const int gn   = blockIdx.x & 63;   // j-slice (0..63)
    const int j0   = gn * JT;
    const int l15  = lane & 15;
    const int lhi  = lane >> 4;

    __shared__ f32x4 red[13 * 64];      // 12 = 3 gates x 4 waves, +1 = i_n (x-part)
    __shared__ float ylds[2][256];      // decode y quarter-row, parity-buffered
    __shared__ float bias_lds[64];

    // ---- persistent W_hh bf16 fragments: 3 gates x 8 K-chunks ----
    bf16x8 wHH[3][8];
    #pragma unroll
    for (int n = 0; n < 3; ++n) {
        const float* wrow = W_hh + (size_t)(n * HID + j0 + l15) * HID;
        #pragma unroll
        for (int c = 0; c < 8; ++c) {
            const float* wr = wrow + kq * 256 + c * 32 + lhi * 8;
            #pragma unroll
            for (int jj = 0; jj < 8; ++jj) wHH[n][c][jj] = (short)f2bf(wr[jj]);
        }
    }
    bf16x8 wXH[3];
    #pragma unroll
    for (int n = 0; n < 3; ++n) {
        const float* wrow = W_ih + (size_t)(n * HID + j0 + l15) * NIN;
        #pragma unroll
        for (int jj = 0; jj < 8; ++jj) {
            const int kk = lhi * 8 + jj;
            wXH[n][jj] = (kk < NIN) ? (short)f2bf(wrow[kk]) : (short)0;
        }
    }
    if (tid < 16) {
        bias_lds[tid]      = b_ih[j0 + tid] + b_hh[j0 + tid];               // r
        bias_lds[16 + tid] = b_ih[HID + j0 + tid] + b_hh[HID + j0 + tid];   // z
        bias_lds[32 + tid] = b_ih[2 * HID + j0 + tid];                      // n (x side)
        bias_lds[48 + tid] = b_hh[2 * HID + j0 + tid];                      // n (h side)
    }
    // ---- fused decode assignment ----
    const int bdec  = gb * BPG + (gn >> 2);
    const int qdec  = gn & 3;
    const int d_del = delays[bdec];
    const int odec  = tid & 31;
    const int jgd   = tid >> 5;
    float wd[32];
    #pragma unroll
    for (int jj = 0; jj < 32; ++jj)
        wd[jj] = (odec < NIN) ? W_dec[(size_t)odec * HID + qdec * 256 + jgd * 32 + jj] : 0.f;

    const int jl = l15;
    const int bl = kq * 4 + lhi;
    const int arow = gb * BPG + l15;    // A-fragment row = batch-in-group

    int* myflag = flags + (gb * 64 + gn) * 16;
    const int* pollflag = flags + (gb * 64 + lane) * 16;  // lane -> one producer WG

    float hprev = 0.f;
    bool dead = false;

    __syncthreads();

    #pragma clang loop unroll(disable)
    for (int t = 0; t < T_STEPS + LAG; ++t) {
        const int target = (t < T_STEPS) ? t : T_STEPS;
        const int t_dec  = t - LAG;
        const int slot_prev  = (t + RINGN  - 1) & (RINGN  - 1);
        const int slot_prevL = (t + RINGLO - 1) & (RINGLO - 1);

        // ---- (A) decode y-row load: data >=7 steps old, visible since poll(t-1)
        unsigned ydw = 0;
        if (t_dec >= 0 && tid < 128) {
            const int tau = (t_dec < d_del) ? t_dec : (t_dec - d_del);
            const unsigned* yrow = (const unsigned*)(ring_hi
                + ((size_t)((tau & (RINGN - 1)) * NBATCH + bdec)) * HID + qdec * 256);
            ld_b32_sys(yrow + tid, ydw);
        }
        // ---- (B) x fragments (wave 0): independent of h, built during the wait
        bf16x8 axH = {}, axL = {};
        if (t < T_STEPS && kq == 0) {
            const float* xr = x + ((size_t)arow * T_STEPS + t) * NIN;
            #pragma unroll
            for (int jj = 0; jj < 8; ++jj) {
                const int kk = lhi * 8 + jj;
                if (kk < NIN) {
                    float f = xr[kk];
                    unsigned short hi = f2bf(f);
                    axH[jj] = (short)hi;
                    axL[jj] = (short)f2bf(f - bf2f(hi));
                }
            }
        }
        __builtin_amdgcn_sched_barrier(0);   // compiler x-waits stay above

        // ---- (C) spin-poll: all 64 producers of this batch group at step t-1
        if (target > 0 && !dead) {
            int iter = 0;
            for (;;) {
                int v = ld_flag_sys(pollflag);
                if (__all(v >= target)) break;
                if (++iter > (1 << 13)) { dead = true; break; }
            }
        }
        wait_vm0();   // free if poll ran; covers t==0 / y / x stragglers

        // ---- (D) issue h ring loads (8 hi + 8 lo), overlap x-MFMAs under them
        u32x4 rawH[8], rawL[8];
        if (t < T_STEPS) {
            const unsigned short* aH = ring_hi + ((size_t)(slot_prev  * NBATCH + arow)) * HID
                                     + kq * 256 + lhi * 8;
            const unsigned short* aL = ring_lo + ((size_t)(slot_prevL * NBATCH + arow)) * HID
                                     + kq * 256 + lhi * 8;
            #pragma unroll
            for (int c = 0; c < 8; ++c) ld_b128_sys(aH + c * 32, rawH[c]);
            #pragma unroll
            for (int c = 0; c < 8; ++c) ld_b128_sys(aL + c * 32, rawL[c]);
        }

        f32x4 acc0 = {0.f, 0.f, 0.f, 0.f};
        f32x4 acc1 = acc0, acc2 = acc0, acc2x = acc0;

        if (t < T_STEPS) {
            if (kq == 0) {              // x-path MFMAs while ring loads fly
                acc0  = __builtin_amdgcn_mfma_f32_16x16x32_bf16(axH, wXH[0], acc0, 0, 0, 0);
                acc1  = __builtin_amdgcn_mfma_f32_16x16x32_bf16(axH, wXH[1], acc1, 0, 0, 0);
                acc2x = __builtin_amdgcn_mfma_f32_16x16x32_bf16(axH, wXH[2], acc2x, 0, 0, 0);
                acc0  = __builtin_amdgcn_mfma_f32_16x16x32_bf16(axL, wXH[0], acc0, 0, 0, 0);
                acc1  = __builtin_amdgcn_mfma_f32_16x16x32_bf16(axL, wXH[1], acc1, 0, 0, 0);
                acc2x = __builtin_amdgcn_mfma_f32_16x16x32_bf16(axL, wXH[2], acc2x, 0, 0, 0);
            }
            wait_vm8();                 // 16 outstanding -> wait for the 8 hi loads
            #pragma unroll
            for (int c = 0; c < 8; ++c) {       // W . h_hi
                bf16x8 a = __builtin_bit_cast(bf16x8, rawH[c]);
                acc0 = __builtin_amdgcn_mfma_f32_16x16x32_bf16(a, wHH[0][c], acc0, 0, 0, 0);
                acc1 = __builtin_amdgcn_mfma_f32_16x16x32_bf16(a, wHH[1][c], acc1, 0, 0, 0);
                acc2 = __builtin_amdgcn_mfma_f32_16x16x32_bf16(a, wHH[2][c], acc2, 0, 0, 0);
            }
            wait_vm0();                 // lo loads done (overlapped with hi MFMAs)
            #pragma unroll
            for (int c = 0; c < 8; ++c) {       // W . h_lo
                bf16x8 a = __builtin_bit_cast(bf16x8, rawL[c]);
                acc0 = __builtin_amdgcn_mfma_f32_16x16x32_bf16(a, wHH[0][c], acc0, 0, 0, 0);
                acc1 = __builtin_amdgcn_mfma_f32_16x16x32_bf16(a, wHH[1][c], acc1, 0, 0, 0);
                acc2 = __builtin_amdgcn_mfma_f32_16x16x32_bf16(a, wHH[2][c], acc2, 0, 0, 0);
            }
            red[(0 * 4 + kq) * 64 + lane] = acc0;
            red[(1 * 4 + kq) * 64 + lane] = acc1;
            red[(2 * 4 + kq) * 64 + lane] = acc2;
            if (kq == 0) red[12 * 64 + lane] = acc2x;
        } else {
            wait_vm0();                 // drain y loads in the tail steps
        }
        if (t_dec >= 0 && tid < 128) {
            ylds[t & 1][2 * tid]     = bf2f((unsigned short)(ydw & 0xFFFFu));
            ylds[t & 1][2 * tid + 1] = bf2f((unsigned short)(ydw >> 16));
        }
        __syncthreads();   // sync1

        if (t < T_STEPS) {
            // reduce 4 K-quarter partials; C layout: col=lane&15, row=(lane>>4)*4+reg
            const float* redf = (const float*)red;
            const int ridx = (jl + 16 * (bl >> 2)) * 4 + (bl & 3);
            float gr = 0.f, gz = 0.f, gh_n = 0.f;
            #pragma unroll
            for (int w = 0; w < 4; ++w) {
                gr   += redf[((0 * 4 + w) * 64) * 4 + ridx];
                gz   += redf[((1 * 4 + w) * 64) * 4 + ridx];
                gh_n += redf[((2 * 4 + w) * 64) * 4 + ridx];
            }
            const float i_n = redf[(12 * 64) * 4 + ridx];
            const float r  = 1.f / (1.f + __expf(-(gr + bias_lds[jl])));
            const float z  = 1.f / (1.f + __expf(-(gz + bias_lds[16 + jl])));
            const float nn = tanhf(i_n + bias_lds[32 + jl] + r * (gh_n + bias_lds[48 + jl]));
            const float hnew = (1.f - z) * nn + z * hprev;
            hprev = hnew;
            // direct 2B stores: this thread owns h[gb*16+bl][j0+jl]
            const unsigned short hih = f2bf(hnew);
            const unsigned short loh = f2bf(hnew - bf2f(hih));
            const int bg = gb * BPG + bl;
            unsigned short* ph = ring_hi + ((size_t)((t & (RINGN - 1)) * NBATCH + bg)) * HID
                               + j0 + jl;
            unsigned short* pl = ring_lo + ((size_t)((t & (RINGLO - 1)) * NBATCH + bg)) * HID
                               + j0 + jl;
            st_b16_sys(ph, (unsigned)hih);
            st_b16_sys(pl, (unsigned)loh);
        }
        wait_vm0();        // drain own h stores to the coherent point
        __syncthreads();   // sync2: whole WG's h is globally visible

        if (t < T_STEPS && tid == 0)
            st_b32_sys(myflag, (unsigned)(t + 1));

        // ---- tail (shadowed by other WGs' polls): decode MACs + atomics
        if (t_dec >= 0) {
            float p = 0.f;
            if (odec < NIN) {
                const float* yrow = ylds[t & 1] + jgd * 32;
                #pragma unroll
                for (int k = 0; k < 32; ++k) p += yrow[k] * wd[k];
            }
            p += __shfl_xor(p, 32);     // fold the wave's two j-groups
            if (lane < 32 && odec < NIN)
                atomicAdd(out + ((size_t)bdec * T_STEPS + t_dec) * NIN + odec, p);
        }
    }
}

__global__ void fill_out_kernel(float* __restrict__ out, const float* __restrict__ b_dec, int n)
{
    int idx = blockIdx.x * blockDim.x + threadIdx.x;
    if (idx < n) out[idx] = b_dec[idx % NIN];
}

extern "C" void kernel_launch(void* const* d_in, const int* in_sizes, int n_in,
                              void* d_out, int out_size, void* d_ws, size_t ws_size,
                              hipStream_t stream)
{
    (void)in_sizes; (void)n_in;
    const float* xx    = (const float*)d_in[0];
    const int*   dl    = (const int*)d_in[1];
    const float* W_ih  = (const float*)d_in[2];
    const float* W_hh  = (const float*)d_in[3];
    const float* b_ih  = (const float*)d_in[4];
    const float* b_hh  = (const float*)d_in[5];
    const float* W_dec = (const float*)d_in[6];
    const float* b_dec = (const float*)d_in[7];
    float* out = (float*)d_out;

    if (ws_size < WS_NEED) return;

    unsigned short* ring_hi = (unsigned short*)d_ws;
    unsigned short* ring_lo = (unsigned short*)((char*)d_ws + RINGHI_BYTES);
    int*            flags   = (int*)((char*)d_ws + RINGHI_BYTES + RINGLO_BYTES);

    const size_t slot_bytes = (size_t)NBATCH * HID * 2;   // 128 KiB
    // zero h(-1) slots (hi ring slot 31, lo ring slot 3) and flags
    hipMemsetAsync((char*)d_ws + (size_t)(RINGN - 1) * slot_bytes, 0, slot_bytes, stream);
    hipMemsetAsync((char*)d_ws + RINGHI_BYTES + (size_t)(RINGLO - 1) * slot_bytes, 0,
                   slot_bytes + FLAGS_BYTES, stream);

    fill_out_kernel<<<dim3((out_size + 255) / 256), dim3(256), 0, stream>>>(out, b_dec, out_size);

    void* args[] = {(void*)&xx, (void*)&dl, (void*)&W_ih, (void*)&W_hh, (void*)&b_ih,
                    (void*)&b_hh, (void*)&W_dec, (void*)&out, (void*)&ring_hi,
                    (void*)&ring_lo, (void*)&flags};
    hipError_t e = hipLaunchCooperativeKernel((void*)gru_persist, dim3(256), dim3(256),
                                              args, 0, stream);
    if (e != hipSuccess) {
        gru_persist<<<dim3(256), dim3(256), 0, stream>>>(xx, dl, W_ih, W_hh, b_ih, b_hh,
                                                         W_dec, out, ring_hi, ring_lo, flags);
    }
}